// Round 7
// baseline (1038.796 us; speedup 1.0000x reference)
//
#include <hip/hip_runtime.h>

#define DIM 384
#define HEADS 12
#define HD 32
#define NTOK 49
#define NWIN 4096
#define MTOT (NWIN*NTOK)   // 200704 = 1568 * 128
#define PSTR 72            // padded LDS row stride (elements) for P and V^T
#define WSTR 18816         // window stride in blob layout: 12*49*32
#define HSTR 1568          // head stride in blob layout: 49*32

typedef __attribute__((ext_vector_type(8))) __bf16 bf16x8;
typedef __attribute__((ext_vector_type(4))) __bf16 bf16x4;
typedef __attribute__((ext_vector_type(4))) float f32x4;

static __device__ __forceinline__ f32x4 mfma16(bf16x8 a, bf16x8 b, f32x4 c) {
  return __builtin_amdgcn_mfma_f32_16x16x32_bf16(a, b, c, 0, 0, 0);
}

// async global->LDS, 16B per lane: dest = lds_base(wave-uniform) + lane*16
static __device__ __forceinline__ void gload_lds16(const void* g, void* l) {
  __builtin_amdgcn_global_load_lds(
      (const __attribute__((address_space(1))) unsigned int*)g,
      (__attribute__((address_space(3))) unsigned int*)l, 16, 0, 0);
}

static __device__ __forceinline__ bf16x4 cvt4(float4 v) {
  bf16x4 t;
  t[0]=(__bf16)v.x; t[1]=(__bf16)v.y; t[2]=(__bf16)v.z; t[3]=(__bf16)v.w;
  return t;
}

// exact division by 49 for r < 2^18  (M = ceil(2^36/49); M*49-2^36 = 62 <= 2^18)
static __device__ __forceinline__ void div49(unsigned r, unsigned& w, unsigned& t) {
  w = (unsigned)(((unsigned long long)r * 1402438302ull) >> 36);
  t = r - w * 49u;
}

// ---------------- prep: weights -> bf16, bias table expand ----------------
__global__ void k_prep(const float* __restrict__ qw, const float* __restrict__ kvw,
                       const float* __restrict__ pw, const float* __restrict__ rel_table,
                       const int* __restrict__ rel_index,
                       __bf16* __restrict__ qw_bf, __bf16* __restrict__ kvw_bf,
                       __bf16* __restrict__ pw_bf, float* __restrict__ bias_pad) {
  int i = blockIdx.x * 256 + threadIdx.x;
  if (i < DIM*DIM)   qw_bf[i] = (__bf16)qw[i];
  if (i < 2*DIM*DIM) kvw_bf[i] = (__bf16)kvw[i];
  if (i < DIM*DIM)   pw_bf[i] = (__bf16)pw[i];
  if (i < HEADS*64*64) {
    int h = i >> 12, rem = i & 4095, q = rem >> 6, k = rem & 63;
    float v;
    if (k >= NTOK)      v = -1e30f;   // key padding: masks softmax for free
    else if (q >= NTOK) v = 0.0f;     // query padding rows are discarded
    else v = rel_table[rel_index[q*NTOK + k] * HEADS + h];
    bias_pad[i] = v;
  }
}

// ---------------- fused QKV GEMM -> blob layout [win][head][49][32] ----------
// Core identical to round 6 (counted-vmcnt pipeline). Epilogue maps each output
// (row, col) to (win, tok, head, dim) via exact magic-div by 49.
__global__ __launch_bounds__(256, 4) void k_qkv(
    const float* __restrict__ x, const float* __restrict__ y,
    const __bf16* __restrict__ qw_bf, const __bf16* __restrict__ kvw_bf,
    const float* __restrict__ q_b, const float* __restrict__ kv_b,
    __bf16* __restrict__ Qws, __bf16* __restrict__ Kws, __bf16* __restrict__ Vws)
{
  // 14112 = 8 * 1764 : bijective XCD swizzle
  int b = blockIdx.x;
  int orig = (b & 7) * 1764 + (b >> 3);
  int mtile = orig / 9;
  int nt9 = orig - mtile*9;
  const float* A; const __bf16* Bw; const float* bias; __bf16* Cout;
  int wrow0, col0;
  if (nt9 < 3) { A = x; Bw = qw_bf; bias = q_b; Cout = Qws; wrow0 = nt9*128; col0 = wrow0; }
  else {
    A = y; Bw = kvw_bf; bias = kv_b; wrow0 = (nt9-3)*128;
    if (wrow0 < DIM) { Cout = Kws; col0 = wrow0; } else { Cout = Vws; col0 = wrow0 - DIM; }
  }
  bias += wrow0;

  __shared__ __align__(16) __bf16 As[2*128*32];   // 2 x 8 KB (double buffer)
  __shared__ __align__(16) __bf16 Bs[3*128*32];   // 3 x 8 KB (ring, 2-deep prefetch)

  int t = threadIdx.x, lane = t & 63, wave = t >> 6;
  int l15 = lane & 15, g = lane >> 4;
  int wr = (wave >> 1) * 64, wc = (wave & 1) * 64;
  int row0b = mtile*128;

  // ---- A staging geometry (coalesced reg path) ----
  int c8 = lane & 7;
  int r8 = lane >> 3;
  int swk = (lane >> 4) & 3;
  const float* asrc = A + (size_t)(row0b + wave*32 + r8)*DIM + c8*4;
  unsigned lwb = (unsigned)wave*2048 + (unsigned)r8*64
               + ((((c8 >> 1) ^ swk) << 4) + (c8 & 1)*8);

  // ---- B staging geometry (global_load_lds, pre-swizzled source) ----
  int sr  = 2*(lane >> 3) + ((lane >> 2) & 1);
  int scb = (lane & 3) ^ ((lane >> 3) & 3);
  const __bf16* bsrc0 = Bw + (size_t)(wrow0 + (wave*2    )*16 + sr)*DIM + scb*8;
  const __bf16* bsrc1 = Bw + (size_t)(wrow0 + (wave*2 + 1)*16 + sr)*DIM + scb*8;

  f32x4 acc[4][4];
  #pragma unroll
  for (int a=0;a<4;a++)
    #pragma unroll
    for (int bb=0;bb<4;bb++) acc[a][bb] = (f32x4){0.f,0.f,0.f,0.f};

  // ---- prologue ----
  {
    float4 s0 = *(const float4*)(asrc);
    float4 s1 = *(const float4*)(asrc +  8*DIM);
    float4 s2 = *(const float4*)(asrc + 16*DIM);
    float4 s3 = *(const float4*)(asrc + 24*DIM);
    gload_lds16(bsrc0,      (char*)Bs +        (wave*2  )*1024);
    gload_lds16(bsrc1,      (char*)Bs +        (wave*2+1)*1024);
    gload_lds16(bsrc0 + 32, (char*)Bs + 8192 + (wave*2  )*1024);
    gload_lds16(bsrc1 + 32, (char*)Bs + 8192 + (wave*2+1)*1024);
    *(bf16x4*)((char*)As + lwb +    0) = cvt4(s0);
    *(bf16x4*)((char*)As + lwb +  512) = cvt4(s1);
    *(bf16x4*)((char*)As + lwb + 1024) = cvt4(s2);
    *(bf16x4*)((char*)As + lwb + 1536) = cvt4(s3);
    asm volatile("s_waitcnt vmcnt(2)" ::: "memory");
    asm volatile("s_waitcnt lgkmcnt(0)" ::: "memory");
    __builtin_amdgcn_s_barrier();
  }

  int lslot = l15*64 + ((g ^ ((l15 >> 1) & 3)) << 4);

  #pragma unroll
  for (int kt = 0; kt < 12; ++kt) {
    const int cur2 = kt & 1, nxt2 = cur2 ^ 1;
    const int cur3 = kt % 3, pre3 = (kt + 2) % 3;
    float4 s0, s1, s2, s3;
    if (kt < 11) {
      int kk = (kt + 1) * 32;
      s0 = *(const float4*)(asrc + kk);
      s1 = *(const float4*)(asrc + kk +  8*DIM);
      s2 = *(const float4*)(asrc + kk + 16*DIM);
      s3 = *(const float4*)(asrc + kk + 24*DIM);
    }
    if (kt < 10) {
      int kk = (kt + 2) * 32;
      gload_lds16(bsrc0 + kk, (char*)Bs + pre3*8192 + (wave*2  )*1024);
      gload_lds16(bsrc1 + kk, (char*)Bs + pre3*8192 + (wave*2+1)*1024);
    }
    bf16x8 af[4], bfv[4];
    #pragma unroll
    for (int a=0;a<4;a++)
      af[a]  = *(const bf16x8*)((const char*)As + cur2*8192 + (wr + a*16)*64 + lslot);
    #pragma unroll
    for (int bb=0;bb<4;bb++)
      bfv[bb] = *(const bf16x8*)((const char*)Bs + cur3*8192 + (wc + bb*16)*64 + lslot);
    #pragma unroll
    for (int a=0;a<4;a++)
      #pragma unroll
      for (int bb=0;bb<4;bb++)
        acc[a][bb] = mfma16(af[a], bfv[bb], acc[a][bb]);
    if (kt < 11) {
      *(bf16x4*)((char*)As + nxt2*8192 + lwb +    0) = cvt4(s0);
      *(bf16x4*)((char*)As + nxt2*8192 + lwb +  512) = cvt4(s1);
      *(bf16x4*)((char*)As + nxt2*8192 + lwb + 1024) = cvt4(s2);
      *(bf16x4*)((char*)As + nxt2*8192 + lwb + 1536) = cvt4(s3);
      if (kt < 10) asm volatile("s_waitcnt vmcnt(2)" ::: "memory");
      else         asm volatile("s_waitcnt vmcnt(0)" ::: "memory");
      asm volatile("s_waitcnt lgkmcnt(0)" ::: "memory");
      __builtin_amdgcn_s_barrier();
    }
  }

  // ---- epilogue: write into blob layout ----
  unsigned wo[4][4];   // win*WSTR + tok*32 per (a, r)
  #pragma unroll
  for (int a=0;a<4;a++)
    #pragma unroll
    for (int r=0;r<4;r++) {
      unsigned row = (unsigned)(row0b + wr + a*16 + 4*g + r);
      unsigned w, tk; div49(row, w, tk);
      wo[a][r] = w*(unsigned)WSTR + tk*32u;
    }
  #pragma unroll
  for (int a=0;a<4;a++) {
    #pragma unroll
    for (int bb=0;bb<4;bb++) {
      int colw = wc + bb*16 + l15;
      int col = col0 + colw;
      unsigned hb = (unsigned)(col >> 5)*(unsigned)HSTR + (unsigned)(col & 31);
      float bi = bias[colw];
      #pragma unroll
      for (int r=0;r<4;r++)
        Cout[wo[a][r] + hb] = (__bf16)(acc[a][bb][r] + bi);
    }
  }
}

// ---------------- per-window attention (12 heads), blob I/O ----------------
// Reads Q/K/V blobs (fully coalesced), writes attn_out OVER the Q blob
// (wave-local head: Q fully consumed before AO write).
__global__ __launch_bounds__(256) void k_attn(
    __bf16* qao,   // Q blob in, AO blob out (ALIASED — intentionally not restrict)
    const __bf16* __restrict__ Kws, const __bf16* __restrict__ Vws,
    const float* __restrict__ bias_pad)
{
  __shared__ __align__(16) __bf16 Psh[4][64*PSTR];
  __shared__ __align__(16) __bf16 VTsh[4][32*PSTR];
  int b = blockIdx.x;
  int lane = threadIdx.x & 63, wave = threadIdx.x >> 6;
  int l15 = lane & 15, g = lane >> 4;
  __bf16* Pw  = Psh[wave];
  __bf16* VTw = VTsh[wave];
  __bf16* Qb = qao + (size_t)b * WSTR;
  const __bf16* Kb = Kws + (size_t)b * WSTR;
  const __bf16* Vb = Vws + (size_t)b * WSTR;
  const float scale = 0.17677669529663687f;  // 32^-0.5

  for (int e = lane; e < 32*15; e += 64) {
    int d = e / 15, k = 49 + (e - d*15);
    VTw[d*PSTR + k] = (__bf16)0.0f;
  }

  for (int hh = 0; hh < 3; hh++) {
    int h = wave + hh*4;
    const __bf16* Qh = Qb + h*HSTR;
    const __bf16* Kh = Kb + h*HSTR;
    const __bf16* Vh = Vb + h*HSTR;
    // stage V^T: blob rows contiguous -> 16B vector loads, scalar transpose writes
    for (int e = lane*8; e < NTOK*HD; e += 512) {
      bf16x8 v = *(const bf16x8*)(Vh + e);
      int tok = e >> 5, d0 = e & 31;
      #pragma unroll
      for (int i=0;i<8;i++) VTw[(d0+i)*PSTR + tok] = v[i];
    }
    bf16x8 qf[4], kf[4];
    #pragma unroll
    for (int mt=0; mt<4; mt++) {
      int q = 16*mt + l15; if (q > 48) q = 48;
      qf[mt] = *(const bf16x8*)(Qh + q*HD + g*8);
    }
    #pragma unroll
    for (int nt=0; nt<4; nt++) {
      int kk = 16*nt + l15; if (kk > 48) kk = 48;
      kf[nt] = *(const bf16x8*)(Kh + kk*HD + g*8);
    }
    f32x4 sacc[4][4];
    #pragma unroll
    for (int mt=0; mt<4; mt++)
      #pragma unroll
      for (int nt=0; nt<4; nt++)
        sacc[mt][nt] = mfma16(qf[mt], kf[nt], (f32x4){0.f,0.f,0.f,0.f});

    const float* bt = bias_pad + h*4096;
    float rs[4][4];
    #pragma unroll
    for (int mt=0; mt<4; mt++) {
      #pragma unroll
      for (int r=0; r<4; r++) {
        int q = 16*mt + 4*g + r;
        float v0 = sacc[mt][0][r]*scale + bt[q*64 +  0 + l15];
        float v1 = sacc[mt][1][r]*scale + bt[q*64 + 16 + l15];
        float v2 = sacc[mt][2][r]*scale + bt[q*64 + 32 + l15];
        float v3 = sacc[mt][3][r]*scale + bt[q*64 + 48 + l15];
        float m = fmaxf(fmaxf(v0,v1), fmaxf(v2,v3));
        #pragma unroll
        for (int off=1; off<16; off<<=1) m = fmaxf(m, __shfl_xor(m, off));
        v0 = __expf(v0-m); v1 = __expf(v1-m); v2 = __expf(v2-m); v3 = __expf(v3-m);
        float s = v0+v1+v2+v3;
        #pragma unroll
        for (int off=1; off<16; off<<=1) s += __shfl_xor(s, off);
        rs[mt][r] = s;
        Pw[q*PSTR +  0 + l15] = (__bf16)v0;
        Pw[q*PSTR + 16 + l15] = (__bf16)v1;
        Pw[q*PSTR + 32 + l15] = (__bf16)v2;
        Pw[q*PSTR + 48 + l15] = (__bf16)v3;
      }
    }

    __bf16* AOh = Qb + h*HSTR;   // overwrite Q blob (fully consumed above)
    #pragma unroll
    for (int mt=0; mt<4; mt++) {
      #pragma unroll
      for (int dt=0; dt<2; dt++) {
        f32x4 o = (f32x4){0.f,0.f,0.f,0.f};
        #pragma unroll
        for (int ks=0; ks<2; ks++) {
          bf16x8 pa = *(const bf16x8*)(Pw  + (16*mt + l15)*PSTR + 32*ks + 8*g);
          bf16x8 vb = *(const bf16x8*)(VTw + (16*dt + l15)*PSTR + 32*ks + 8*g);
          o = mfma16(pa, vb, o);
        }
        #pragma unroll
        for (int r=0; r<4; r++) {
          int q = 16*mt + 4*g + r;
          if (q < NTOK)
            AOh[q*HD + 16*dt + l15] = (__bf16)(o[r] / rs[mt][r]);
        }
      }
    }
  }
}

// ---------------- output projection: A from AO blob, counted-vmcnt ----------
__global__ __launch_bounds__(256, 4) void k_proj(
    const __bf16* __restrict__ Aao, const __bf16* __restrict__ pw_bf,
    const float* __restrict__ pb, float* __restrict__ out)
{
  // 4704 = 8 * 588 : bijective XCD swizzle
  int b = blockIdx.x;
  int orig = (b & 7) * 588 + (b >> 3);
  int mtile = orig / 3;
  int nt = orig - mtile*3;
  int lane = threadIdx.x & 63, wave = threadIdx.x >> 6;
  int l15 = lane & 15, g = lane >> 4;
  int wr = (wave >> 1) * 64, wc = (wave & 1) * 64;
  int row0b = mtile*128;
  int col00 = nt*128;

  __shared__ __align__(16) __bf16 As[3*128*32];   // 3 x 8 KB ring
  __shared__ __align__(16) __bf16 Bs[3*128*32];   // 3 x 8 KB ring

  int sr  = 2*(lane >> 3) + ((lane >> 2) & 1);
  int scb = (lane & 3) ^ ((lane >> 3) & 3);
  // A source: AO blob — K-step kt reads head kt's 32 dims: stride HSTR per kt
  const __bf16* asrc0; const __bf16* asrc1;
  {
    unsigned r0 = (unsigned)(row0b + (wave*2    )*16 + sr);
    unsigned r1 = (unsigned)(row0b + (wave*2 + 1)*16 + sr);
    unsigned w0, t0, w1, t1; div49(r0, w0, t0); div49(r1, w1, t1);
    asrc0 = Aao + (size_t)w0*WSTR + t0*32 + scb*8;
    asrc1 = Aao + (size_t)w1*WSTR + t1*32 + scb*8;
  }
  const __bf16* bsrc0 = pw_bf + (size_t)(col00 + (wave*2    )*16 + sr)*DIM + scb*8;
  const __bf16* bsrc1 = pw_bf + (size_t)(col00 + (wave*2 + 1)*16 + sr)*DIM + scb*8;

  f32x4 acc[4][4];
  #pragma unroll
  for (int a=0;a<4;a++)
    #pragma unroll
    for (int bb=0;bb<4;bb++) acc[a][bb] = (f32x4){0.f,0.f,0.f,0.f};

  // prologue: stage batches 0 and 1; wait batch 0 only
  {
    gload_lds16(asrc0,        (char*)As +        (wave*2  )*1024);
    gload_lds16(asrc1,        (char*)As +        (wave*2+1)*1024);
    gload_lds16(bsrc0,        (char*)Bs +        (wave*2  )*1024);
    gload_lds16(bsrc1,        (char*)Bs +        (wave*2+1)*1024);
    gload_lds16(asrc0 + HSTR, (char*)As + 8192 + (wave*2  )*1024);
    gload_lds16(asrc1 + HSTR, (char*)As + 8192 + (wave*2+1)*1024);
    gload_lds16(bsrc0 + 32,   (char*)Bs + 8192 + (wave*2  )*1024);
    gload_lds16(bsrc1 + 32,   (char*)Bs + 8192 + (wave*2+1)*1024);
    asm volatile("s_waitcnt vmcnt(4)" ::: "memory");
    __builtin_amdgcn_s_barrier();
  }

  int lslot = l15*64 + ((g ^ ((l15 >> 1) & 3)) << 4);

  #pragma unroll
  for (int kt = 0; kt < 12; ++kt) {
    const int cur3 = kt % 3, pre3 = (kt + 2) % 3;
    if (kt < 10) {
      int ka = (kt + 2) * HSTR;
      int kb = (kt + 2) * 32;
      gload_lds16(asrc0 + ka, (char*)As + pre3*8192 + (wave*2  )*1024);
      gload_lds16(asrc1 + ka, (char*)As + pre3*8192 + (wave*2+1)*1024);
      gload_lds16(bsrc0 + kb, (char*)Bs + pre3*8192 + (wave*2  )*1024);
      gload_lds16(bsrc1 + kb, (char*)Bs + pre3*8192 + (wave*2+1)*1024);
    }
    bf16x8 af[4], bfv[4];
    #pragma unroll
    for (int a=0;a<4;a++)
      af[a]  = *(const bf16x8*)((const char*)As + cur3*8192 + (wr + a*16)*64 + lslot);
    #pragma unroll
    for (int bb=0;bb<4;bb++)
      bfv[bb] = *(const bf16x8*)((const char*)Bs + cur3*8192 + (wc + bb*16)*64 + lslot);
    #pragma unroll
    for (int a=0;a<4;a++)
      #pragma unroll
      for (int bb=0;bb<4;bb++)
        acc[a][bb] = mfma16(af[a], bfv[bb], acc[a][bb]);
    if (kt < 11) {
      if (kt < 10) asm volatile("s_waitcnt vmcnt(4)" ::: "memory");
      else         asm volatile("s_waitcnt vmcnt(0)" ::: "memory");
      __builtin_amdgcn_s_barrier();
    }
  }

  #pragma unroll
  for (int a=0;a<4;a++) {
    #pragma unroll
    for (int bb=0;bb<4;bb++) {
      int col = col00 + wc + bb*16 + l15;
      float bi = pb[col];
      size_t cbase = (size_t)(row0b + wr + a*16 + 4*g)*DIM + col;
      #pragma unroll
      for (int r=0;r<4;r++)
        out[cbase + (size_t)r*DIM] = acc[a][bb][r] + bi;
    }
  }
}

extern "C" void kernel_launch(void* const* d_in, const int* in_sizes, int n_in,
                              void* d_out, int out_size, void* d_ws, size_t ws_size,
                              hipStream_t stream)
{
  const float* x   = (const float*)d_in[0];
  const float* y   = (const float*)d_in[1];
  const float* qw  = (const float*)d_in[2];
  const float* qb  = (const float*)d_in[3];
  const float* kvw = (const float*)d_in[4];
  const float* kvb = (const float*)d_in[5];
  const float* pw  = (const float*)d_in[6];
  const float* pb  = (const float*)d_in[7];
  const float* rt  = (const float*)d_in[8];
  const int*   ri  = (const int*)d_in[9];
  float* out = (float*)d_out;

  char* ws = (char*)d_ws;
  const size_t WS_NEEDED = 1376256ull + 3ull*154140672ull;
  if (ws_size < WS_NEEDED) return;

  __bf16* qw_bf    = (__bf16*)(ws);
  __bf16* kvw_bf   = (__bf16*)(ws + 294912);
  __bf16* pw_bf    = (__bf16*)(ws + 884736);
  float*  bias_pad = (float*)(ws + 1179648);
  __bf16* Qws      = (__bf16*)(ws + 1376256);   // Q blob, later AO blob
  __bf16* Kws      = Qws + (size_t)MTOT*DIM;
  __bf16* Vws      = Kws + (size_t)MTOT*DIM;

  k_prep<<<dim3(1152), dim3(256), 0, stream>>>(qw, kvw, pw, rt, ri, qw_bf, kvw_bf, pw_bf, bias_pad);
  k_qkv <<<dim3(1568*9), dim3(256), 0, stream>>>(x, y, qw_bf, kvw_bf, qb, kvb, Qws, Kws, Vws);
  k_attn<<<dim3(NWIN), dim3(256), 0, stream>>>(Qws, Kws, Vws, bias_pad);
  k_proj<<<dim3(1568*3), dim3(256), 0, stream>>>(Qws, pw_bf, pb, out);
}

// Round 8
// 851.625 us; speedup vs baseline: 1.2198x; 1.2198x over previous
//
#include <hip/hip_runtime.h>

#define DIM 384
#define HEADS 12
#define HD 32
#define NTOK 49
#define NWIN 4096
#define MTOT (NWIN*NTOK)   // 200704 = 784 * 256
#define PSTR 72            // padded LDS row stride (elements) for P and V^T

typedef __attribute__((ext_vector_type(8))) __bf16 bf16x8;
typedef __attribute__((ext_vector_type(4))) __bf16 bf16x4;
typedef __attribute__((ext_vector_type(4))) float f32x4;

static __device__ __forceinline__ f32x4 mfma16(bf16x8 a, bf16x8 b, f32x4 c) {
  return __builtin_amdgcn_mfma_f32_16x16x32_bf16(a, b, c, 0, 0, 0);
}

// async global->LDS, 16B per lane: dest = lds_base(wave-uniform) + lane*16
static __device__ __forceinline__ void gload_lds16(const void* g, void* l) {
  __builtin_amdgcn_global_load_lds(
      (const __attribute__((address_space(1))) unsigned int*)g,
      (__attribute__((address_space(3))) unsigned int*)l, 16, 0, 0);
}

static __device__ __forceinline__ bf16x4 cvt4(float4 v) {
  bf16x4 t;
  t[0]=(__bf16)v.x; t[1]=(__bf16)v.y; t[2]=(__bf16)v.z; t[3]=(__bf16)v.w;
  return t;
}

// ---------------- prep: weights -> bf16, bias table expand ----------------
__global__ void k_prep(const float* __restrict__ qw, const float* __restrict__ kvw,
                       const float* __restrict__ pw, const float* __restrict__ rel_table,
                       const int* __restrict__ rel_index,
                       __bf16* __restrict__ qw_bf, __bf16* __restrict__ kvw_bf,
                       __bf16* __restrict__ pw_bf, float* __restrict__ bias_pad) {
  int i = blockIdx.x * 256 + threadIdx.x;
  if (i < DIM*DIM)   qw_bf[i] = (__bf16)qw[i];
  if (i < 2*DIM*DIM) kvw_bf[i] = (__bf16)kvw[i];
  if (i < DIM*DIM)   pw_bf[i] = (__bf16)pw[i];
  if (i < HEADS*64*64) {
    int h = i >> 12, rem = i & 4095, q = rem >> 6, k = rem & 63;
    float v;
    if (k >= NTOK)      v = -1e30f;   // key padding: masks softmax for free
    else if (q >= NTOK) v = 0.0f;     // query padding rows are discarded
    else v = rel_table[rel_index[q*NTOK + k] * HEADS + h];
    bias_pad[i] = v;
  }
}

// ---------------- fused QKV GEMM: 256x128 tile, 8 waves, counted vmcnt ------
// A (f32): reg-staged 1 step ahead, coalesced (8 lanes cover one 128B row),
// cvt->ds_write into 2-buffer swizzled LDS (256 rows x 64B). B (bf16 weights):
// 1 gload_lds/wave/step into 3-buffer ring, 2 steps ahead. Row-major outputs.
__global__ __launch_bounds__(512, 4) void k_qkv(
    const float* __restrict__ x, const float* __restrict__ y,
    const __bf16* __restrict__ qw_bf, const __bf16* __restrict__ kvw_bf,
    const float* __restrict__ q_b, const float* __restrict__ kv_b,
    __bf16* __restrict__ Qws, __bf16* __restrict__ Kws, __bf16* __restrict__ Vws)
{
  // 7056 = 8 * 882 : bijective XCD swizzle; 9 col-tiles of one mtile on one XCD
  int b = blockIdx.x;
  int orig = (b & 7) * 882 + (b >> 3);
  int mtile = orig / 9;
  int nt9 = orig - mtile*9;
  const float* A; const __bf16* Bw; const float* bias; __bf16* Cout;
  int wrow0, col0;
  if (nt9 < 3) { A = x; Bw = qw_bf; bias = q_b; Cout = Qws; wrow0 = nt9*128; col0 = wrow0; }
  else {
    A = y; Bw = kvw_bf; bias = kv_b; wrow0 = (nt9-3)*128;
    if (wrow0 < DIM) { Cout = Kws; col0 = wrow0; } else { Cout = Vws; col0 = wrow0 - DIM; }
  }
  bias += wrow0;

  __shared__ __align__(16) __bf16 As[2*256*32];   // 2 x 16 KB (double buffer)
  __shared__ __align__(16) __bf16 Bs[3*128*32];   // 3 x  8 KB (ring, 2-deep)

  int t = threadIdx.x, lane = t & 63, wave = t >> 6;    // 8 waves
  int l15 = lane & 15, g = lane >> 4;
  int wrM = (wave >> 1) * 64;        // 4 M-subtiles of 64
  int wcN = (wave & 1) * 64;         // 2 N-subtiles of 64
  int row0b = mtile*256;

  // ---- A staging geometry: instr j covers rows wave*8 + j*64 + r8 ----
  int c8 = lane & 7;            // 16B chunk within the 128B f32 row
  int r8 = lane >> 3;           // row within the 8-row instruction group
  int swk = ((wave*8 + r8) >> 1) & 3;   // swizzle key, invariant under +64
  const float* asrc = A + (size_t)(row0b + wave*8 + r8)*DIM + c8*4;
  unsigned lwb = (unsigned)(wave*8 + r8)*64
               + ((((c8 >> 1) ^ swk) << 4) + (c8 & 1)*8);

  // ---- B staging: one gload_lds16 per wave per step (16 rows x 64B) ----
  int sr  = 2*(lane >> 3) + ((lane >> 2) & 1);
  int scb = (lane & 3) ^ ((lane >> 3) & 3);
  const __bf16* bsrc = Bw + (size_t)(wrow0 + wave*16 + sr)*DIM + scb*8;

  f32x4 acc[4][4];
  #pragma unroll
  for (int a=0;a<4;a++)
    #pragma unroll
    for (int bb=0;bb<4;bb++) acc[a][bb] = (f32x4){0.f,0.f,0.f,0.f};

  // ---- prologue: A(0) regs; B(0),B(1) gloads; commit A(0); counted wait ----
  {
    float4 s0 = *(const float4*)(asrc);
    float4 s1 = *(const float4*)(asrc +  64*DIM);
    float4 s2 = *(const float4*)(asrc + 128*DIM);
    float4 s3 = *(const float4*)(asrc + 192*DIM);
    gload_lds16(bsrc,      (char*)Bs +        wave*1024);
    gload_lds16(bsrc + 32, (char*)Bs + 8192 + wave*1024);
    *(bf16x4*)((char*)As + lwb +     0) = cvt4(s0);
    *(bf16x4*)((char*)As + lwb +  4096) = cvt4(s1);
    *(bf16x4*)((char*)As + lwb +  8192) = cvt4(s2);
    *(bf16x4*)((char*)As + lwb + 12288) = cvt4(s3);
    asm volatile("s_waitcnt vmcnt(1)" ::: "memory");   // B(0) done; B(1) flying
    asm volatile("s_waitcnt lgkmcnt(0)" ::: "memory");
    __builtin_amdgcn_s_barrier();
  }

  int lslot = l15*64 + ((g ^ ((l15 >> 1) & 3)) << 4);

  #pragma unroll
  for (int kt = 0; kt < 12; ++kt) {
    const int cur2 = kt & 1, nxt2 = cur2 ^ 1;
    const int cur3 = kt % 3, pre3 = (kt + 2) % 3;
    float4 s0, s1, s2, s3;
    if (kt < 11) {             // A loads for kt+1, issued EARLY
      int kk = (kt + 1) * 32;
      s0 = *(const float4*)(asrc + kk);
      s1 = *(const float4*)(asrc + kk +  64*DIM);
      s2 = *(const float4*)(asrc + kk + 128*DIM);
      s3 = *(const float4*)(asrc + kk + 192*DIM);
    }
    if (kt < 10)               // B gload for kt+2 (2-deep ring)
      gload_lds16(bsrc + (kt + 2)*32, (char*)Bs + pre3*8192 + wave*1024);

    bf16x8 af[4], bfv[4];
    #pragma unroll
    for (int a=0;a<4;a++)
      af[a]  = *(const bf16x8*)((const char*)As + cur2*16384 + (wrM + a*16)*64 + lslot);
    #pragma unroll
    for (int bb=0;bb<4;bb++)
      bfv[bb] = *(const bf16x8*)((const char*)Bs + cur3*8192 + (wcN + bb*16)*64 + lslot);
    #pragma unroll
    for (int a=0;a<4;a++)
      #pragma unroll
      for (int bb=0;bb<4;bb++)
        acc[a][bb] = mfma16(af[a], bfv[bb], acc[a][bb]);

    if (kt < 11) {
      // write-late: compiler's wait for s0..s3 lands at vmcnt(1) — drains
      // B(kt+1)+A(kt+1); B(kt+2) stays in flight across the barrier.
      *(bf16x4*)((char*)As + nxt2*16384 + lwb +     0) = cvt4(s0);
      *(bf16x4*)((char*)As + nxt2*16384 + lwb +  4096) = cvt4(s1);
      *(bf16x4*)((char*)As + nxt2*16384 + lwb +  8192) = cvt4(s2);
      *(bf16x4*)((char*)As + nxt2*16384 + lwb + 12288) = cvt4(s3);
      if (kt < 10) asm volatile("s_waitcnt vmcnt(1)" ::: "memory");
      else         asm volatile("s_waitcnt vmcnt(0)" ::: "memory");
      asm volatile("s_waitcnt lgkmcnt(0)" ::: "memory");
      __builtin_amdgcn_s_barrier();
    }
  }

  #pragma unroll
  for (int a=0;a<4;a++) {
    #pragma unroll
    for (int bb=0;bb<4;bb++) {
      int colw = wcN + bb*16 + l15;
      float bi = bias[colw];
      size_t cbase = (size_t)(row0b + wrM + a*16 + 4*g)*DIM + (col0 + colw);
      #pragma unroll
      for (int r=0;r<4;r++)
        Cout[cbase + (size_t)r*DIM] = (__bf16)(acc[a][bb][r] + bi);
    }
  }
}

// ---------------- per-window attention (12 heads), writes attn_out over Q ----------------
__global__ __launch_bounds__(256) void k_attn(
    __bf16* qao,   // Q in, attn_out out (ALIASED — intentionally not restrict)
    const __bf16* __restrict__ Kws, const __bf16* __restrict__ Vws,
    const float* __restrict__ bias_pad)
{
  __shared__ __align__(16) __bf16 Psh[4][64*PSTR];
  __shared__ __align__(16) __bf16 VTsh[4][32*PSTR];
  int b = blockIdx.x;
  int lane = threadIdx.x & 63, wave = threadIdx.x >> 6;
  int l15 = lane & 15, g = lane >> 4;
  __bf16* Pw  = Psh[wave];
  __bf16* VTw = VTsh[wave];
  size_t rowbase = (size_t)b * NTOK * DIM;
  const float scale = 0.17677669529663687f;  // 32^-0.5

  for (int e = lane; e < 32*15; e += 64) {
    int d = e / 15, k = 49 + (e - d*15);
    VTw[d*PSTR + k] = (__bf16)0.0f;
  }

  for (int hh = 0; hh < 3; hh++) {
    int h = wave + hh*4;
    for (int e = lane; e < NTOK*HD; e += 64) {
      int k = e >> 5, d = e & 31;
      VTw[d*PSTR + k] = Vws[rowbase + (size_t)k*DIM + h*HD + d];
    }
    bf16x8 qf[4], kf[4];
    #pragma unroll
    for (int mt=0; mt<4; mt++) {
      int q = 16*mt + l15; if (q > 48) q = 48;
      qf[mt] = *(const bf16x8*)(qao + rowbase + (size_t)q*DIM + h*HD + g*8);
    }
    #pragma unroll
    for (int nt=0; nt<4; nt++) {
      int kk = 16*nt + l15; if (kk > 48) kk = 48;
      kf[nt] = *(const bf16x8*)(Kws + rowbase + (size_t)kk*DIM + h*HD + g*8);
    }
    f32x4 sacc[4][4];
    #pragma unroll
    for (int mt=0; mt<4; mt++)
      #pragma unroll
      for (int nt=0; nt<4; nt++)
        sacc[mt][nt] = mfma16(qf[mt], kf[nt], (f32x4){0.f,0.f,0.f,0.f});

    const float* bt = bias_pad + h*4096;
    float rs[4][4];
    #pragma unroll
    for (int mt=0; mt<4; mt++) {
      #pragma unroll
      for (int r=0; r<4; r++) {
        int q = 16*mt + 4*g + r;
        float v0 = sacc[mt][0][r]*scale + bt[q*64 +  0 + l15];
        float v1 = sacc[mt][1][r]*scale + bt[q*64 + 16 + l15];
        float v2 = sacc[mt][2][r]*scale + bt[q*64 + 32 + l15];
        float v3 = sacc[mt][3][r]*scale + bt[q*64 + 48 + l15];
        float m = fmaxf(fmaxf(v0,v1), fmaxf(v2,v3));
        #pragma unroll
        for (int off=1; off<16; off<<=1) m = fmaxf(m, __shfl_xor(m, off));
        v0 = __expf(v0-m); v1 = __expf(v1-m); v2 = __expf(v2-m); v3 = __expf(v3-m);
        float s = v0+v1+v2+v3;
        #pragma unroll
        for (int off=1; off<16; off<<=1) s += __shfl_xor(s, off);
        rs[mt][r] = s;
        Pw[q*PSTR +  0 + l15] = (__bf16)v0;
        Pw[q*PSTR + 16 + l15] = (__bf16)v1;
        Pw[q*PSTR + 32 + l15] = (__bf16)v2;
        Pw[q*PSTR + 48 + l15] = (__bf16)v3;
      }
    }

    #pragma unroll
    for (int mt=0; mt<4; mt++) {
      #pragma unroll
      for (int dt=0; dt<2; dt++) {
        f32x4 o = (f32x4){0.f,0.f,0.f,0.f};
        #pragma unroll
        for (int ks=0; ks<2; ks++) {
          bf16x8 pa = *(const bf16x8*)(Pw  + (16*mt + l15)*PSTR + 32*ks + 8*g);
          bf16x8 vb = *(const bf16x8*)(VTw + (16*dt + l15)*PSTR + 32*ks + 8*g);
          o = mfma16(pa, vb, o);
        }
        #pragma unroll
        for (int r=0; r<4; r++) {
          int q = 16*mt + 4*g + r;
          if (q < NTOK)
            qao[rowbase + (size_t)q*DIM + h*HD + 16*dt + l15] = (__bf16)(o[r] / rs[mt][r]);
        }
      }
    }
  }
}

// ---------------- output projection: counted-vmcnt pipeline, 3-buffer rings ----
__global__ __launch_bounds__(256, 4) void k_proj(
    const __bf16* __restrict__ Aao, const __bf16* __restrict__ pw_bf,
    const float* __restrict__ pb, float* __restrict__ out)
{
  // 4704 = 8 * 588 : bijective XCD swizzle
  int b = blockIdx.x;
  int orig = (b & 7) * 588 + (b >> 3);
  int mtile = orig / 3;
  int nt = orig - mtile*3;
  int lane = threadIdx.x & 63, wave = threadIdx.x >> 6;
  int l15 = lane & 15, g = lane >> 4;
  int wr = (wave >> 1) * 64, wc = (wave & 1) * 64;
  int row0b = mtile*128;
  int col00 = nt*128;

  __shared__ __align__(16) __bf16 As[3*128*32];   // 3 x 8 KB ring
  __shared__ __align__(16) __bf16 Bs[3*128*32];   // 3 x 8 KB ring

  int sr  = 2*(lane >> 3) + ((lane >> 2) & 1);
  int scb = (lane & 3) ^ ((lane >> 3) & 3);
  const __bf16* asrc0 = Aao   + (size_t)(row0b + (wave*2    )*16 + sr)*DIM + scb*8;
  const __bf16* asrc1 = Aao   + (size_t)(row0b + (wave*2 + 1)*16 + sr)*DIM + scb*8;
  const __bf16* bsrc0 = pw_bf + (size_t)(col00 + (wave*2    )*16 + sr)*DIM + scb*8;
  const __bf16* bsrc1 = pw_bf + (size_t)(col00 + (wave*2 + 1)*16 + sr)*DIM + scb*8;

  f32x4 acc[4][4];
  #pragma unroll
  for (int a=0;a<4;a++)
    #pragma unroll
    for (int bb=0;bb<4;bb++) acc[a][bb] = (f32x4){0.f,0.f,0.f,0.f};

  // prologue: stage batches 0 and 1; wait batch 0 only
  {
    gload_lds16(asrc0,      (char*)As +        (wave*2  )*1024);
    gload_lds16(asrc1,      (char*)As +        (wave*2+1)*1024);
    gload_lds16(bsrc0,      (char*)Bs +        (wave*2  )*1024);
    gload_lds16(bsrc1,      (char*)Bs +        (wave*2+1)*1024);
    gload_lds16(asrc0 + 32, (char*)As + 8192 + (wave*2  )*1024);
    gload_lds16(asrc1 + 32, (char*)As + 8192 + (wave*2+1)*1024);
    gload_lds16(bsrc0 + 32, (char*)Bs + 8192 + (wave*2  )*1024);
    gload_lds16(bsrc1 + 32, (char*)Bs + 8192 + (wave*2+1)*1024);
    asm volatile("s_waitcnt vmcnt(4)" ::: "memory");   // batch 0 done; batch 1 flying
    __builtin_amdgcn_s_barrier();
  }

  int lslot = l15*64 + ((g ^ ((l15 >> 1) & 3)) << 4);

  #pragma unroll
  for (int kt = 0; kt < 12; ++kt) {
    const int cur3 = kt % 3, pre3 = (kt + 2) % 3;
    if (kt < 10) {
      int kk = (kt + 2) * 32;
      gload_lds16(asrc0 + kk, (char*)As + pre3*8192 + (wave*2  )*1024);
      gload_lds16(asrc1 + kk, (char*)As + pre3*8192 + (wave*2+1)*1024);
      gload_lds16(bsrc0 + kk, (char*)Bs + pre3*8192 + (wave*2  )*1024);
      gload_lds16(bsrc1 + kk, (char*)Bs + pre3*8192 + (wave*2+1)*1024);
    }
    bf16x8 af[4], bfv[4];
    #pragma unroll
    for (int a=0;a<4;a++)
      af[a]  = *(const bf16x8*)((const char*)As + cur3*8192 + (wr + a*16)*64 + lslot);
    #pragma unroll
    for (int bb=0;bb<4;bb++)
      bfv[bb] = *(const bf16x8*)((const char*)Bs + cur3*8192 + (wc + bb*16)*64 + lslot);
    #pragma unroll
    for (int a=0;a<4;a++)
      #pragma unroll
      for (int bb=0;bb<4;bb++)
        acc[a][bb] = mfma16(af[a], bfv[bb], acc[a][bb]);
    if (kt < 11) {
      if (kt < 10) asm volatile("s_waitcnt vmcnt(4)" ::: "memory");
      else         asm volatile("s_waitcnt vmcnt(0)" ::: "memory");
      __builtin_amdgcn_s_barrier();
    }
  }

  #pragma unroll
  for (int a=0;a<4;a++) {
    #pragma unroll
    for (int bb=0;bb<4;bb++) {
      int col = col00 + wc + bb*16 + l15;
      float bi = pb[col];
      size_t cbase = (size_t)(row0b + wr + a*16 + 4*g)*DIM + col;
      #pragma unroll
      for (int r=0;r<4;r++)
        out[cbase + (size_t)r*DIM] = acc[a][bb][r] + bi;
    }
  }
}

extern "C" void kernel_launch(void* const* d_in, const int* in_sizes, int n_in,
                              void* d_out, int out_size, void* d_ws, size_t ws_size,
                              hipStream_t stream)
{
  const float* x   = (const float*)d_in[0];
  const float* y   = (const float*)d_in[1];
  const float* qw  = (const float*)d_in[2];
  const float* qb  = (const float*)d_in[3];
  const float* kvw = (const float*)d_in[4];
  const float* kvb = (const float*)d_in[5];
  const float* pw  = (const float*)d_in[6];
  const float* pb  = (const float*)d_in[7];
  const float* rt  = (const float*)d_in[8];
  const int*   ri  = (const int*)d_in[9];
  float* out = (float*)d_out;

  char* ws = (char*)d_ws;
  const size_t WS_NEEDED = 1376256ull + 3ull*154140672ull;
  if (ws_size < WS_NEEDED) return;

  __bf16* qw_bf    = (__bf16*)(ws);
  __bf16* kvw_bf   = (__bf16*)(ws + 294912);
  __bf16* pw_bf    = (__bf16*)(ws + 884736);
  float*  bias_pad = (float*)(ws + 1179648);
  __bf16* Qws      = (__bf16*)(ws + 1376256);
  __bf16* Kws      = Qws + (size_t)MTOT*DIM;
  __bf16* Vws      = Kws + (size_t)MTOT*DIM;

  k_prep<<<dim3(1152), dim3(256), 0, stream>>>(qw, kvw, pw, rt, ri, qw_bf, kvw_bf, pw_bf, bias_pad);
  k_qkv <<<dim3(784*9), dim3(512), 0, stream>>>(x, y, qw_bf, kvw_bf, qb, kvb, Qws, Kws, Vws);
  k_attn<<<dim3(NWIN), dim3(256), 0, stream>>>(Qws, Kws, Vws, bias_pad);
  k_proj<<<dim3(1568*3), dim3(256), 0, stream>>>(Qws, pw_bf, pb, out);
}